// Round 3
// baseline (361.171 us; speedup 1.0000x reference)
//
#include <hip/hip_runtime.h>
#include <hip/hip_bf16.h>

// Problem: B=2, T=2048, D=1024, H=16, HD=64.
// Reference is fp32; harness dtype ambiguous -> runtime-detect fp32 vs bf16
// and canonicalize inputs to bf16 in ws. Output written per detected dtype.

#define TB 2
#define TT 2048
#define TD 1024
#define TH 16
#define TM (TB * TT) // 4096

#define NEG_BIG (-1e30f)

typedef __attribute__((ext_vector_type(8))) short short8;
typedef __attribute__((ext_vector_type(4))) float f32x4;

__device__ __forceinline__ short f2bf(float f) {
    __hip_bfloat16 h = __float2bfloat16(f);
    return __builtin_bit_cast(short, h);
}

__device__ __forceinline__ float safe_exp(float d) {
    return expf(fmaxf(d, -80.f));
}

// ---------------------------------------------------------------------------
// Dtype detection: sample even-indexed u16s of x. bf16 data -> sane exponent
// fields; fp32 data -> even u16s are low-mantissa shorts, uniform exponents.
// ---------------------------------------------------------------------------
__global__ void detect_kernel(const unsigned short* __restrict__ xq, int* __restrict__ flag)
{
    int lane = threadIdx.x; // 64 threads
    unsigned short u = xq[lane * 2];
    int e = (u >> 7) & 0xFF;
    int sane = ((e >= 100 && e <= 145) || u == 0) ? 1 : 0;
    unsigned long long b = __ballot(sane);
    if (lane == 0) *flag = (__popcll(b) >= 48) ? 1 : 0; // 1 = bf16, 0 = fp32
}

// ---------------------------------------------------------------------------
// Canonicalize one tensor to bf16 (copy if already bf16, round if fp32).
// n must be a multiple of 2048 (it is: 4M or 1M).
// ---------------------------------------------------------------------------
__global__ __launch_bounds__(256) void convert_kernel(
    const void* __restrict__ src, short* __restrict__ dst, int n,
    const int* __restrict__ flag)
{
    int i = (blockIdx.x * 256 + threadIdx.x) * 8;
    if (i >= n) return;
    if (*flag) {
        *(short8*)(dst + i) = *(const short8*)((const short*)src + i);
    } else {
        const float* s = (const float*)src + i;
        short8 o;
        #pragma unroll
        for (int j = 0; j < 8; ++j) o[j] = f2bf(s[j]);
        *(short8*)(dst + i) = o;
    }
}

// ---------------------------------------------------------------------------
// QKV projection: C[m,n] = sum_k x[m,k] * W[n,k]; out in [B,H,T,64] layout.
// grid: (M/64, N/64, 3), block 256 (4 waves), each wave: 16(M) x 64(N).
// ---------------------------------------------------------------------------
__global__ __launch_bounds__(256) void qkv_gemm_kernel(
    const short* __restrict__ x,
    const short* __restrict__ Wq, const short* __restrict__ Wk,
    const short* __restrict__ Wv,
    short* __restrict__ Qo, short* __restrict__ Ko, short* __restrict__ Vo)
{
    const short* W = (blockIdx.z == 0) ? Wq : (blockIdx.z == 1) ? Wk : Wv;
    short* Out = (blockIdx.z == 0) ? Qo : (blockIdx.z == 1) ? Ko : Vo;

    __shared__ __align__(16) short As[64][72];
    __shared__ __align__(16) short Bs[64][72];

    const int tid = threadIdx.x;
    const int wave = tid >> 6, lane = tid & 63;
    const int mbase = blockIdx.x * 64, nbase = blockIdx.y * 64;
    const int lr = lane & 15;
    const int lk = (lane >> 4) * 8;

    f32x4 acc[4] = {{0,0,0,0},{0,0,0,0},{0,0,0,0},{0,0,0,0}};

    for (int k0 = 0; k0 < TD; k0 += 64) {
        for (int c = tid; c < 512; c += 256) {
            int r = c >> 3, col = (c & 7) * 8;
            *(short8*)&As[r][col] = *(const short8*)&x[(size_t)(mbase + r) * TD + k0 + col];
            *(short8*)&Bs[r][col] = *(const short8*)&W[(size_t)(nbase + r) * TD + k0 + col];
        }
        __syncthreads();
        #pragma unroll
        for (int kk = 0; kk < 64; kk += 32) {
            short8 af = *(const short8*)&As[wave * 16 + lr][kk + lk];
            #pragma unroll
            for (int c = 0; c < 4; ++c) {
                short8 bf = *(const short8*)&Bs[c * 16 + lr][kk + lk];
                acc[c] = __builtin_amdgcn_mfma_f32_16x16x32_bf16(af, bf, acc[c], 0, 0, 0);
            }
        }
        __syncthreads();
    }

    // C/D layout: row = (lane>>4)*4 + i, col = lane&15  [verified m89/m91]
    const int rq = (lane >> 4) * 4;
    #pragma unroll
    for (int c = 0; c < 4; ++c) {
        #pragma unroll
        for (int i = 0; i < 4; ++i) {
            int m = mbase + wave * 16 + rq + i;
            int n = nbase + c * 16 + lr;
            int b = m >> 11, t = m & (TT - 1);
            int h = n >> 6, hd = n & 63;
            Out[(((size_t)(b * TH + h) * TT + t) << 6) + hd] = f2bf(acc[c][i]);
        }
    }
}

// ---------------------------------------------------------------------------
// Output projection: C[m,n] = sum_k A[m,k] * Wo[n,k]; writes d_out per flag.
// ---------------------------------------------------------------------------
__global__ __launch_bounds__(256) void out_gemm_kernel(
    const short* __restrict__ A, const short* __restrict__ W,
    void* __restrict__ C, const int* __restrict__ flag)
{
    __shared__ __align__(16) short As[64][72];
    __shared__ __align__(16) short Bs[64][72];

    const int tid = threadIdx.x;
    const int wave = tid >> 6, lane = tid & 63;
    const int mbase = blockIdx.x * 64, nbase = blockIdx.y * 64;
    const int lr = lane & 15;
    const int lk = (lane >> 4) * 8;

    f32x4 acc[4] = {{0,0,0,0},{0,0,0,0},{0,0,0,0},{0,0,0,0}};

    for (int k0 = 0; k0 < TD; k0 += 64) {
        for (int c = tid; c < 512; c += 256) {
            int r = c >> 3, col = (c & 7) * 8;
            *(short8*)&As[r][col] = *(const short8*)&A[(size_t)(mbase + r) * TD + k0 + col];
            *(short8*)&Bs[r][col] = *(const short8*)&W[(size_t)(nbase + r) * TD + k0 + col];
        }
        __syncthreads();
        #pragma unroll
        for (int kk = 0; kk < 64; kk += 32) {
            short8 af = *(const short8*)&As[wave * 16 + lr][kk + lk];
            #pragma unroll
            for (int c = 0; c < 4; ++c) {
                short8 bf = *(const short8*)&Bs[c * 16 + lr][kk + lk];
                acc[c] = __builtin_amdgcn_mfma_f32_16x16x32_bf16(af, bf, acc[c], 0, 0, 0);
            }
        }
        __syncthreads();
    }

    const int rq = (lane >> 4) * 4;
    const int f = *flag; // uniform
    #pragma unroll
    for (int c = 0; c < 4; ++c) {
        #pragma unroll
        for (int i = 0; i < 4; ++i) {
            int m = mbase + wave * 16 + rq + i;
            int n = nbase + c * 16 + lr;
            if (f) ((short*)C)[(size_t)m * TD + n] = f2bf(acc[c][i]);
            else   ((float*)C)[(size_t)m * TD + n] = acc[c][i];
        }
    }
}

// ---------------------------------------------------------------------------
// Flash attention (causal). grid: (T/64, B*H), block 256.
// Q,K,V in [B,H,T,64] bf16; writes [B,T,D] bf16. Inf-free.
// ---------------------------------------------------------------------------
__global__ __launch_bounds__(256) void attn_kernel(
    const short* __restrict__ Q, const short* __restrict__ K,
    const short* __restrict__ V, short* __restrict__ AO)
{
    const int bh = blockIdx.y;
    const int qbase = blockIdx.x * 64;
    const short* Qp = Q + (size_t)bh * TT * 64;
    const short* Kp = K + (size_t)bh * TT * 64;
    const short* Vp = V + (size_t)bh * TT * 64;

    __shared__ __align__(16) short Ks[64][72];
    __shared__ __align__(16) short Vt[64][72];
    __shared__ __align__(16) short Ps[4][16][72];

    const int tid = threadIdx.x;
    const int wave = tid >> 6, lane = tid & 63;
    const int lr = lane & 15;
    const int lk = (lane >> 4) * 8;
    const int g4 = (lane >> 4) * 4;

    const int qrowA = qbase + wave * 16 + lr;
    const short8 qf0 = *(const short8*)&Qp[(size_t)qrowA * 64 + lk];
    const short8 qf1 = *(const short8*)&Qp[(size_t)qrowA * 64 + 32 + lk];

    f32x4 Oa[4] = {{0,0,0,0},{0,0,0,0},{0,0,0,0},{0,0,0,0}};
    float m_i[4] = {NEG_BIG, NEG_BIG, NEG_BIG, NEG_BIG};
    float l_i[4] = {0.f, 0.f, 0.f, 0.f};

    const int kend = qbase + 64;
    for (int kt = 0; kt < kend; kt += 64) {
        for (int c = tid; c < 512; c += 256) {
            int r = c >> 3, col = (c & 7) * 8;
            *(short8*)&Ks[r][col] = *(const short8*)&Kp[(size_t)(kt + r) * 64 + col];
            short8 vv = *(const short8*)&Vp[(size_t)(kt + r) * 64 + col];
            #pragma unroll
            for (int j = 0; j < 8; ++j) Vt[col + j][r] = vv[j];
        }
        __syncthreads();

        f32x4 s[4];
        #pragma unroll
        for (int c = 0; c < 4; ++c) {
            f32x4 z = {0, 0, 0, 0};
            short8 b0 = *(const short8*)&Ks[c * 16 + lr][lk];
            short8 b1 = *(const short8*)&Ks[c * 16 + lr][32 + lk];
            z = __builtin_amdgcn_mfma_f32_16x16x32_bf16(qf0, b0, z, 0, 0, 0);
            z = __builtin_amdgcn_mfma_f32_16x16x32_bf16(qf1, b1, z, 0, 0, 0);
            s[c] = z;
        }

        const bool diag = (kt == qbase);
        #pragma unroll
        for (int c = 0; c < 4; ++c) {
            int colg = kt + c * 16 + lr;
            #pragma unroll
            for (int i = 0; i < 4; ++i) {
                float v = s[c][i] * 0.125f; // 1/sqrt(64)
                if (diag) {
                    int rowg = qbase + wave * 16 + g4 + i;
                    if (colg > rowg) v = NEG_BIG;
                }
                s[c][i] = v;
            }
        }

        float mnew[4], alpha[4];
        #pragma unroll
        for (int i = 0; i < 4; ++i) {
            float v = fmaxf(fmaxf(s[0][i], s[1][i]), fmaxf(s[2][i], s[3][i]));
            #pragma unroll
            for (int off = 1; off < 16; off <<= 1)
                v = fmaxf(v, __shfl_xor(v, off, 64));
            mnew[i] = fmaxf(m_i[i], v);
            alpha[i] = safe_exp(m_i[i] - mnew[i]);
            m_i[i] = mnew[i];
        }

        #pragma unroll
        for (int c = 0; c < 4; ++c) {
            #pragma unroll
            for (int i = 0; i < 4; ++i) {
                float p = safe_exp(s[c][i] - mnew[i]);
                s[c][i] = p;
                Ps[wave][g4 + i][c * 16 + lr] = f2bf(p);
            }
        }
        #pragma unroll
        for (int i = 0; i < 4; ++i) {
            float v = s[0][i] + s[1][i] + s[2][i] + s[3][i];
            #pragma unroll
            for (int off = 1; off < 16; off <<= 1)
                v += __shfl_xor(v, off, 64);
            l_i[i] = l_i[i] * alpha[i] + v;
        }
        #pragma unroll
        for (int c = 0; c < 4; ++c)
            #pragma unroll
            for (int i = 0; i < 4; ++i)
                Oa[c][i] *= alpha[i];

        __syncthreads();

        #pragma unroll
        for (int kk = 0; kk < 2; ++kk) {
            short8 af = *(const short8*)&Ps[wave][lr][kk * 32 + lk];
            #pragma unroll
            for (int c = 0; c < 4; ++c) {
                short8 bf = *(const short8*)&Vt[c * 16 + lr][kk * 32 + lk];
                Oa[c] = __builtin_amdgcn_mfma_f32_16x16x32_bf16(af, bf, Oa[c], 0, 0, 0);
            }
        }
        __syncthreads();
    }

    const int b = bh >> 4, h = bh & 15;
    #pragma unroll
    for (int c = 0; c < 4; ++c) {
        #pragma unroll
        for (int i = 0; i < 4; ++i) {
            int qr = qbase + wave * 16 + g4 + i;
            float v = Oa[c][i] / l_i[i];
            AO[((size_t)(b * TT + qr) << 10) + h * 64 + c * 16 + lr] = f2bf(v);
        }
    }
}

// ---------------------------------------------------------------------------
extern "C" void kernel_launch(void* const* d_in, const int* in_sizes, int n_in,
                              void* d_out, int out_size, void* d_ws, size_t ws_size,
                              hipStream_t stream)
{
    char* ws = (char*)d_ws;
    int* flag = (int*)ws;
    const size_t XB  = (size_t)TM * TD * 2;   // 8 MiB bf16 x
    const size_t WB  = (size_t)TD * TD * 2;   // 2 MiB bf16 weight
    const size_t BUF = (size_t)TM * TD * 2;   // 8 MiB activation

    short* xb  = (short*)(ws + 256);
    short* Wqb = (short*)(ws + 256 + XB);
    short* Wkb = (short*)(ws + 256 + XB + WB);
    short* Wvb = (short*)(ws + 256 + XB + 2 * WB);
    short* Wob = (short*)(ws + 256 + XB + 3 * WB);
    char*  act = ws + 256 + XB + 4 * WB;
    short* Qb = (short*)(act);
    short* Kb = (short*)(act + BUF);
    short* Vb = (short*)(act + 2 * BUF);
    short* Ab = (short*)(act + 3 * BUF);

    detect_kernel<<<1, 64, 0, stream>>>((const unsigned short*)d_in[0], flag);

    const int NX = TM * TD, NW = TD * TD;
    convert_kernel<<<NX / 2048, 256, 0, stream>>>(d_in[0], xb,  NX, flag);
    convert_kernel<<<NW / 2048, 256, 0, stream>>>(d_in[1], Wqb, NW, flag);
    convert_kernel<<<NW / 2048, 256, 0, stream>>>(d_in[2], Wkb, NW, flag);
    convert_kernel<<<NW / 2048, 256, 0, stream>>>(d_in[3], Wvb, NW, flag);
    convert_kernel<<<NW / 2048, 256, 0, stream>>>(d_in[4], Wob, NW, flag);

    dim3 blk(256);
    qkv_gemm_kernel<<<dim3(TM / 64, TD / 64, 3), blk, 0, stream>>>(xb, Wqb, Wkb, Wvb, Qb, Kb, Vb);
    attn_kernel<<<dim3(TT / 64, TB * TH), blk, 0, stream>>>(Qb, Kb, Vb, Ab);
    out_gemm_kernel<<<dim3(TM / 64, TD / 64), blk, 0, stream>>>(Ab, Wob, d_out, flag);
}

// Round 4
// 268.766 us; speedup vs baseline: 1.3438x; 1.3438x over previous
//
#include <hip/hip_runtime.h>
#include <hip/hip_bf16.h>

// Problem: B=2, T=2048, D=1024, H=16, HD=64.
// Runtime-detect fp32 vs bf16 inputs; canonicalize to bf16 in ws.
// Pipeline: convert -> qkv gemm (Q,K: [B,H,T,64]; V: transposed [B,H,64,T])
//        -> flash attention (paired q-tiles, exp2 softmax) -> out gemm.

#define TB 2
#define TT 2048
#define TD 1024
#define TH 16
#define TM (TB * TT) // 4096

#define NEG_BIG (-1e30f)
#define SCALE_LOG2 0.18033688f  // (1/sqrt(64)) * log2(e)

typedef __attribute__((ext_vector_type(8))) short short8;
typedef __attribute__((ext_vector_type(4))) float f32x4;

__device__ __forceinline__ short f2bf(float f) {
    __hip_bfloat16 h = __float2bfloat16(f);
    return __builtin_bit_cast(short, h);
}

__device__ __forceinline__ float fast_exp2(float x) {
#if __has_builtin(__builtin_amdgcn_exp2f)
    return __builtin_amdgcn_exp2f(x);   // v_exp_f32: 2^x, large-neg -> 0, no NaN
#else
    return exp2f(x);
#endif
}

// ---------------------------------------------------------------------------
// Dtype detection: sample even-indexed u16s of x. bf16 data -> sane exponents.
// ---------------------------------------------------------------------------
__global__ void detect_kernel(const unsigned short* __restrict__ xq, int* __restrict__ flag)
{
    int lane = threadIdx.x; // 64 threads
    unsigned short u = xq[lane * 2];
    int e = (u >> 7) & 0xFF;
    int sane = ((e >= 100 && e <= 145) || u == 0) ? 1 : 0;
    unsigned long long b = __ballot(sane);
    if (lane == 0) *flag = (__popcll(b) >= 48) ? 1 : 0; // 1 = bf16, 0 = fp32
}

// ---------------------------------------------------------------------------
// Canonicalize one tensor to bf16 (copy if already bf16, round if fp32).
// ---------------------------------------------------------------------------
__global__ __launch_bounds__(256) void convert_kernel(
    const void* __restrict__ src, short* __restrict__ dst, int n,
    const int* __restrict__ flag)
{
    int i = (blockIdx.x * 256 + threadIdx.x) * 8;
    if (i >= n) return;
    if (*flag) {
        *(short8*)(dst + i) = *(const short8*)((const short*)src + i);
    } else {
        const float* s = (const float*)src + i;
        short8 o;
        #pragma unroll
        for (int j = 0; j < 8; ++j) o[j] = f2bf(s[j]);
        *(short8*)(dst + i) = o;
    }
}

// ---------------------------------------------------------------------------
// QKV projection: C[m,n] = sum_k x[m,k] * W[n,k].
// Q,K out: [B,H,T,64].  V out: TRANSPOSED [B,H,64,T] (for conflict-free PV).
// grid: (M/64, N/64, 3), block 256 (4 waves), each wave: 16(M) x 64(N).
// ---------------------------------------------------------------------------
__global__ __launch_bounds__(256) void qkv_gemm_kernel(
    const short* __restrict__ x,
    const short* __restrict__ Wq, const short* __restrict__ Wk,
    const short* __restrict__ Wv,
    short* __restrict__ Qo, short* __restrict__ Ko, short* __restrict__ Vo)
{
    const short* W = (blockIdx.z == 0) ? Wq : (blockIdx.z == 1) ? Wk : Wv;
    short* Out = (blockIdx.z == 0) ? Qo : (blockIdx.z == 1) ? Ko : Vo;
    const bool transposeV = (blockIdx.z == 2);

    __shared__ __align__(16) short As[64][72];
    __shared__ __align__(16) short Bs[64][72];

    const int tid = threadIdx.x;
    const int wave = tid >> 6, lane = tid & 63;
    const int mbase = blockIdx.x * 64, nbase = blockIdx.y * 64;
    const int lr = lane & 15;
    const int lk = (lane >> 4) * 8;

    f32x4 acc[4] = {{0,0,0,0},{0,0,0,0},{0,0,0,0},{0,0,0,0}};

    for (int k0 = 0; k0 < TD; k0 += 64) {
        for (int c = tid; c < 512; c += 256) {
            int r = c >> 3, col = (c & 7) * 8;
            *(short8*)&As[r][col] = *(const short8*)&x[(size_t)(mbase + r) * TD + k0 + col];
            *(short8*)&Bs[r][col] = *(const short8*)&W[(size_t)(nbase + r) * TD + k0 + col];
        }
        __syncthreads();
        #pragma unroll
        for (int kk = 0; kk < 64; kk += 32) {
            short8 af = *(const short8*)&As[wave * 16 + lr][kk + lk];
            #pragma unroll
            for (int c = 0; c < 4; ++c) {
                short8 bf = *(const short8*)&Bs[c * 16 + lr][kk + lk];
                acc[c] = __builtin_amdgcn_mfma_f32_16x16x32_bf16(af, bf, acc[c], 0, 0, 0);
            }
        }
        __syncthreads();
    }

    // C/D layout: row = (lane>>4)*4 + i, col = lane&15  [verified m89/m91]
    const int rq = (lane >> 4) * 4;
    #pragma unroll
    for (int c = 0; c < 4; ++c) {
        #pragma unroll
        for (int i = 0; i < 4; ++i) {
            int m = mbase + wave * 16 + rq + i;
            int n = nbase + c * 16 + lr;
            int b = m >> 11, t = m & (TT - 1);
            int h = n >> 6, hd = n & 63;
            size_t idx;
            if (transposeV)
                idx = ((size_t)(b * TH + h) * 64 + hd) * TT + t;       // V^T [b,h,hd,t]
            else
                idx = (((size_t)(b * TH + h) * TT + t) << 6) + hd;     // [b,h,t,hd]
            Out[idx] = f2bf(acc[c][i]);
        }
    }
}

// ---------------------------------------------------------------------------
// Output projection: C[m,n] = sum_k A[m,k] * Wo[n,k]; writes d_out per flag.
// ---------------------------------------------------------------------------
__global__ __launch_bounds__(256) void out_gemm_kernel(
    const short* __restrict__ A, const short* __restrict__ W,
    void* __restrict__ C, const int* __restrict__ flag)
{
    __shared__ __align__(16) short As[64][72];
    __shared__ __align__(16) short Bs[64][72];

    const int tid = threadIdx.x;
    const int wave = tid >> 6, lane = tid & 63;
    const int mbase = blockIdx.x * 64, nbase = blockIdx.y * 64;
    const int lr = lane & 15;
    const int lk = (lane >> 4) * 8;

    f32x4 acc[4] = {{0,0,0,0},{0,0,0,0},{0,0,0,0},{0,0,0,0}};

    for (int k0 = 0; k0 < TD; k0 += 64) {
        for (int c = tid; c < 512; c += 256) {
            int r = c >> 3, col = (c & 7) * 8;
            *(short8*)&As[r][col] = *(const short8*)&A[(size_t)(mbase + r) * TD + k0 + col];
            *(short8*)&Bs[r][col] = *(const short8*)&W[(size_t)(nbase + r) * TD + k0 + col];
        }
        __syncthreads();
        #pragma unroll
        for (int kk = 0; kk < 64; kk += 32) {
            short8 af = *(const short8*)&As[wave * 16 + lr][kk + lk];
            #pragma unroll
            for (int c = 0; c < 4; ++c) {
                short8 bf = *(const short8*)&Bs[c * 16 + lr][kk + lk];
                acc[c] = __builtin_amdgcn_mfma_f32_16x16x32_bf16(af, bf, acc[c], 0, 0, 0);
            }
        }
        __syncthreads();
    }

    const int rq = (lane >> 4) * 4;
    const int f = *flag; // uniform
    #pragma unroll
    for (int c = 0; c < 4; ++c) {
        #pragma unroll
        for (int i = 0; i < 4; ++i) {
            int m = mbase + wave * 16 + rq + i;
            int n = nbase + c * 16 + lr;
            if (f) ((short*)C)[(size_t)m * TD + n] = f2bf(acc[c][i]);
            else   ((float*)C)[(size_t)m * TD + n] = acc[c][i];
        }
    }
}

// ---------------------------------------------------------------------------
// Flash attention (causal). grid: (T/128, B*H), block 256.
// Each block processes q-tiles {x, 31-x} sequentially -> exactly 33 k-tiles
// per block (perfect load balance). Q,K: [B,H,T,64]; V: [B,H,64,T] (V^T).
// exp2-domain online softmax, inf-free.
// ---------------------------------------------------------------------------
__global__ __launch_bounds__(256) void attn_kernel(
    const short* __restrict__ Q, const short* __restrict__ K,
    const short* __restrict__ V, short* __restrict__ AO)
{
    const int bh = blockIdx.y;
    const short* Qp = Q + (size_t)bh * TT * 64;
    const short* Kp = K + (size_t)bh * TT * 64;
    const short* Vp = V + (size_t)bh * 64 * TT;   // V^T: [64][TT]

    __shared__ __align__(16) short Ks[64][72];    // [s][hd]
    __shared__ __align__(16) short Vt[64][72];    // [hd][s]
    __shared__ __align__(16) short Ps[4][16][72]; // per-wave P tile [qrow][s]

    const int tid = threadIdx.x;
    const int wave = tid >> 6, lane = tid & 63;
    const int lr = lane & 15;
    const int lk = (lane >> 4) * 8;
    const int g4 = (lane >> 4) * 4;
    const int b = bh >> 4, h = bh & 15;

    for (int half = 0; half < 2; ++half) {
        const int qtile = half ? (31 - blockIdx.x) : blockIdx.x;
        const int qbase = qtile * 64;

        const int qrowA = qbase + wave * 16 + lr;
        const short8 qf0 = *(const short8*)&Qp[(size_t)qrowA * 64 + lk];
        const short8 qf1 = *(const short8*)&Qp[(size_t)qrowA * 64 + 32 + lk];

        f32x4 Oa[4] = {{0,0,0,0},{0,0,0,0},{0,0,0,0},{0,0,0,0}};
        float m_i[4] = {NEG_BIG, NEG_BIG, NEG_BIG, NEG_BIG};
        float l_i[4] = {0.f, 0.f, 0.f, 0.f};

        const int kend = qbase + 64;
        for (int kt = 0; kt < kend; kt += 64) {
            // stage K tile [s][hd] and V^T tile [hd][s] — both coalesced b128
            for (int c = tid; c < 512; c += 256) {
                int r = c >> 3, col = (c & 7) * 8;
                *(short8*)&Ks[r][col] = *(const short8*)&Kp[(size_t)(kt + r) * 64 + col];
                *(short8*)&Vt[r][col] = *(const short8*)&Vp[(size_t)r * TT + kt + col];
            }
            __syncthreads();

            // S = Q K^T, scaled into log2 domain
            f32x4 s[4];
            #pragma unroll
            for (int c = 0; c < 4; ++c) {
                f32x4 z = {0, 0, 0, 0};
                short8 b0 = *(const short8*)&Ks[c * 16 + lr][lk];
                short8 b1 = *(const short8*)&Ks[c * 16 + lr][32 + lk];
                z = __builtin_amdgcn_mfma_f32_16x16x32_bf16(qf0, b0, z, 0, 0, 0);
                z = __builtin_amdgcn_mfma_f32_16x16x32_bf16(qf1, b1, z, 0, 0, 0);
                s[c] = z;
            }

            const bool diag = (kt == qbase);
            #pragma unroll
            for (int c = 0; c < 4; ++c) {
                int colg = kt + c * 16 + lr;
                #pragma unroll
                for (int i = 0; i < 4; ++i) {
                    float v = s[c][i] * SCALE_LOG2;
                    if (diag) {
                        int rowg = qbase + wave * 16 + g4 + i;
                        if (colg > rowg) v = NEG_BIG;
                    }
                    s[c][i] = v;
                }
            }

            // online softmax (log2 domain): row max over 64 cols
            float mnew[4], alpha[4];
            #pragma unroll
            for (int i = 0; i < 4; ++i) {
                float v = fmaxf(fmaxf(s[0][i], s[1][i]), fmaxf(s[2][i], s[3][i]));
                #pragma unroll
                for (int off = 1; off < 16; off <<= 1)
                    v = fmaxf(v, __shfl_xor(v, off, 64));
                mnew[i] = fmaxf(m_i[i], v);
                alpha[i] = fast_exp2(m_i[i] - mnew[i]); // first tile: 2^(-huge) = 0
                m_i[i] = mnew[i];
            }

            // P = 2^(S - m)
            #pragma unroll
            for (int c = 0; c < 4; ++c) {
                #pragma unroll
                for (int i = 0; i < 4; ++i) {
                    float p = fast_exp2(s[c][i] - mnew[i]);
                    s[c][i] = p;
                    Ps[wave][g4 + i][c * 16 + lr] = f2bf(p);
                }
            }
            #pragma unroll
            for (int i = 0; i < 4; ++i) {
                float v = s[0][i] + s[1][i] + s[2][i] + s[3][i];
                #pragma unroll
                for (int off = 1; off < 16; off <<= 1)
                    v += __shfl_xor(v, off, 64);
                l_i[i] = l_i[i] * alpha[i] + v;
            }
            #pragma unroll
            for (int c = 0; c < 4; ++c)
                #pragma unroll
                for (int i = 0; i < 4; ++i)
                    Oa[c][i] *= alpha[i];

            __syncthreads(); // P visibility before MFMA reads

            // O += P V  (P as A-operand from LDS, V^T as B-operand)
            #pragma unroll
            for (int kk = 0; kk < 2; ++kk) {
                short8 af = *(const short8*)&Ps[wave][lr][kk * 32 + lk];
                #pragma unroll
                for (int c = 0; c < 4; ++c) {
                    short8 bf = *(const short8*)&Vt[c * 16 + lr][kk * 32 + lk];
                    Oa[c] = __builtin_amdgcn_mfma_f32_16x16x32_bf16(af, bf, Oa[c], 0, 0, 0);
                }
            }
            __syncthreads(); // protect Ks/Vt before next stage / next half
        }

        // epilogue: normalize, write to [B,T,D] (col = h*64 + hd)
        #pragma unroll
        for (int c = 0; c < 4; ++c) {
            #pragma unroll
            for (int i = 0; i < 4; ++i) {
                int qr = qbase + wave * 16 + g4 + i;
                float v = Oa[c][i] / l_i[i];
                AO[((size_t)(b * TT + qr) << 10) + h * 64 + c * 16 + lr] = f2bf(v);
            }
        }
    }
}

// ---------------------------------------------------------------------------
extern "C" void kernel_launch(void* const* d_in, const int* in_sizes, int n_in,
                              void* d_out, int out_size, void* d_ws, size_t ws_size,
                              hipStream_t stream)
{
    char* ws = (char*)d_ws;
    int* flag = (int*)ws;
    const size_t XB  = (size_t)TM * TD * 2;   // 8 MiB bf16 x
    const size_t WB  = (size_t)TD * TD * 2;   // 2 MiB bf16 weight
    const size_t BUF = (size_t)TM * TD * 2;   // 8 MiB activation

    short* xb  = (short*)(ws + 256);
    short* Wqb = (short*)(ws + 256 + XB);
    short* Wkb = (short*)(ws + 256 + XB + WB);
    short* Wvb = (short*)(ws + 256 + XB + 2 * WB);
    short* Wob = (short*)(ws + 256 + XB + 3 * WB);
    char*  act = ws + 256 + XB + 4 * WB;
    short* Qb = (short*)(act);
    short* Kb = (short*)(act + BUF);
    short* Vb = (short*)(act + 2 * BUF);   // holds V^T [B,H,64,T]
    short* Ab = (short*)(act + 3 * BUF);

    detect_kernel<<<1, 64, 0, stream>>>((const unsigned short*)d_in[0], flag);

    const int NX = TM * TD, NW = TD * TD;
    convert_kernel<<<NX / 2048, 256, 0, stream>>>(d_in[0], xb,  NX, flag);
    convert_kernel<<<NW / 2048, 256, 0, stream>>>(d_in[1], Wqb, NW, flag);
    convert_kernel<<<NW / 2048, 256, 0, stream>>>(d_in[2], Wkb, NW, flag);
    convert_kernel<<<NW / 2048, 256, 0, stream>>>(d_in[3], Wvb, NW, flag);
    convert_kernel<<<NW / 2048, 256, 0, stream>>>(d_in[4], Wob, NW, flag);

    dim3 blk(256);
    qkv_gemm_kernel<<<dim3(TM / 64, TD / 64, 3), blk, 0, stream>>>(xb, Wqb, Wkb, Wvb, Qb, Kb, Vb);
    attn_kernel<<<dim3(TT / 128, TB * TH), blk, 0, stream>>>(Qb, Kb, Vb, Ab);
    out_gemm_kernel<<<dim3(TM / 64, TD / 64), blk, 0, stream>>>(Ab, Wob, d_out, flag);
}